// Round 1
// baseline (150.242 us; speedup 1.0000x reference)
//
#include <hip/hip_runtime.h>

// B=4, L=2048, H=8, E=D=64, fp32 sparse attention over <=47 analytic
// candidates (LocalLogSymmetryMask at L=2048: window -5..+5 plus log
// offsets +-(5+F), F = {1,2,3,5,7,11,17,25,38,57,86,129,194,291,437,656,
// 985,1477}); range-clipping is exactly equivalent to the reference's edge
// branches + monotone breaks.  Wave = 4 groups x 16 lanes; group g owns
// candidates c=4t+g (t=0..11); lane e4=lane&15 owns elements 4*e4..4*e4+3.
//
// Round-12: kill the DS pipe + give the regalloc headroom.
//  * Intra-16-lane dot reductions -> DPP row_ror:{1,2,4,8} adds: pure VALU,
//    no ds_bpermute, no lgkmcnt chains, result broadcast to the whole row.
//  * xor16/xor32 combines -> v_permlane16/32_swap_b32 (gfx950 VALU ops,
//    1.2x vs ds_bpermute per learn_hip m255).  DS-op count/wave: ~58 -> 0.
//  * Byte-scaled candidate offsets with one umin clamp: ~5 VALU/candidate
//    (was ~7 + a shl per load); K and V share the offset registers.
//  * 1.f/d -> v_rcp_f32 (uniform scale, <=1 ulp; saves the ~10-op exact
//    division sequence).
//  * __launch_bounds__(256,6): R11's 32-VGPR allocation forced chunked
//    gather scheduling; 6 waves/EU floor (= the measured 75% occupancy)
//    allows ~85 VGPR so all 12 K rows stay in flight before the dots.

#define KB 4
#define KL 2048
#define KH 8
#define KE 64
#define KWAVES 4
#define KROWS (KB * KL * KH)
#define KBLOCKS (KROWS / KWAVES)  // 16384
#define KROWB (KH * KE * 4)       // 2048 bytes between consecutive j rows

// Candidate offsets (rows): c 0..10 window (c-5); 11..28 left logs -(5+F);
// 29..46 right logs +(5+F); 47 dummy (always out of range; *KROWB = 2^30).
static constexpr int kOff[48] = {
    -5, -4, -3, -2, -1, 0, 1, 2, 3, 4, 5,
    -6, -7, -8, -10, -12, -16, -22, -30, -43, -62, -91, -134, -199, -296,
    -442, -661, -990, -1482,
    6, 7, 8, 10, 12, 16, 22, 30, 43, 62, 91, 134, 199, 296, 442, 661, 990,
    1482,
    1 << 19};

// DPP row-rotate add: after ror 1,2,4,8 every lane of each 16-lane row
// holds the full row sum.  Pure VALU, no DS.
template <int CTRL>
__device__ __forceinline__ float dpp_radd(float x) {
    int t = __builtin_amdgcn_update_dpp(0, __float_as_int(x), CTRL, 0xF, 0xF,
                                        false);
    return x + __int_as_float(t);
}

// permlane16_swap(x,x): res0 = rows {0,0,2,2}, res1 = rows {1,1,3,3} (16-lane
// rows) -> res0 OP res1 == x OP shfl_xor(x,16) in every lane.  Same shape for
// permlane32_swap with the 32-lane halves.
#if __has_builtin(__builtin_amdgcn_permlane16_swap)
__device__ __forceinline__ void pl16(float x, float& a, float& b) {
    auto r = __builtin_amdgcn_permlane16_swap(__float_as_uint(x),
                                              __float_as_uint(x), false, false);
    a = __uint_as_float(r[0]);
    b = __uint_as_float(r[1]);
}
#else
__device__ __forceinline__ void pl16(float x, float& a, float& b) {
    a = x;
    b = __shfl_xor(x, 16, 64);
}
#endif

#if __has_builtin(__builtin_amdgcn_permlane32_swap)
__device__ __forceinline__ void pl32(float x, float& a, float& b) {
    auto r = __builtin_amdgcn_permlane32_swap(__float_as_uint(x),
                                              __float_as_uint(x), false, false);
    a = __uint_as_float(r[0]);
    b = __uint_as_float(r[1]);
}
#else
__device__ __forceinline__ void pl32(float x, float& a, float& b) {
    a = x;
    b = __shfl_xor(x, 32, 64);
}
#endif

__device__ __forceinline__ float red16_add(float x) {
    float a, b;
    pl16(x, a, b);
    return a + b;
}
__device__ __forceinline__ float red32_add(float x) {
    float a, b;
    pl32(x, a, b);
    return a + b;
}
__device__ __forceinline__ float red16_max(float x) {
    float a, b;
    pl16(x, a, b);
    return fmaxf(a, b);
}
__device__ __forceinline__ float red32_max(float x) {
    float a, b;
    pl32(x, a, b);
    return fmaxf(a, b);
}

__global__ __launch_bounds__(256, 6) void MaskAttention_20572893347881_kernel(
    const float* __restrict__ q, const float* __restrict__ k,
    const float* __restrict__ v, float* __restrict__ out) {
    const int tid  = (int)threadIdx.x;
    const int lane = tid & 63;
    const int g    = lane >> 4;  // candidate group 0..3
    const int e4   = lane & 15;  // element-quad index 0..15
    // Wave id in an SGPR: i/h/b provably wave-uniform -> scalar bases,
    // saddr-form loads with 32-bit voffsets.
    const int wave = __builtin_amdgcn_readfirstlane(tid >> 6);

    // XCD-locality swizzle (bijection on [0,16384) blocks).
    const int p = (int)blockIdx.x;
    const int l = (p & 7) * (KBLOCKS / 8) + (p >> 3);
    const int r = l * KWAVES + wave;  // [0, 65536); adjacent i in one block
    const int i = r & (KL - 1);
    const int h = (r >> 11) & (KH - 1);
    const int b = r >> 14;

    const unsigned hbB = (unsigned)b * (unsigned)(KL * KROWB) +
                         (unsigned)h * (unsigned)(KE * 4);
    const char* __restrict__ qc = (const char*)q + hbB;
    const char* __restrict__ kc = (const char*)k + hbB;
    const char* __restrict__ vc = (const char*)v + hbB;
    char* __restrict__ oc       = (char*)out + hbB;

    const unsigned co     = (unsigned)(e4 * 16);              // bytes in row
    const unsigned base   = (unsigned)i * (unsigned)KROWB + co;
    const unsigned clampv = (unsigned)((KL - 1) * KROWB) + co;

    const bool g1 = (g & 1) != 0;
    const bool g2 = (g & 2) != 0;

    // ---- candidate byte offsets (32-bit, umin-clamped) ----
    unsigned off[12];
    bool ok[12];
#pragma unroll
    for (int t = 0; t < 12; ++t) {
        const int a0 = kOff[4 * t + 0] * KROWB;
        const int a1 = kOff[4 * t + 1] * KROWB;
        const int a2 = kOff[4 * t + 2] * KROWB;
        const int a3 = kOff[4 * t + 3] * KROWB;
        const int dd = g1 ? (g2 ? a3 : a1) : (g2 ? a2 : a0);
        const unsigned u = base + (unsigned)dd;
        // valid iff 0 <= i+dd < L  <=>  u < L*KROWB  (co < KROWB)
        ok[t]  = u < (unsigned)(KL * KROWB);
        off[t] = u < clampv ? u : clampv;  // invalid -> row 2047, weight 0
    }

    // ---- Q first (critical path), then all K loads in flight ----
    float4 qf = *(const float4*)(qc + base);
    float4 kf[12];
#pragma unroll
    for (int t = 0; t < 12; ++t) kf[t] = *(const float4*)(kc + off[t]);
    qf.x *= 0.125f;
    qf.y *= 0.125f;
    qf.z *= 0.125f;
    qf.w *= 0.125f;

    // ---- independent partial dots (frees kf) ----
    float s[12];
#pragma unroll
    for (int t = 0; t < 12; ++t)
        s[t] = qf.x * kf[t].x + qf.y * kf[t].y + qf.z * kf[t].z +
               qf.w * kf[t].w;

    // ---- V loads issued; DPP reductions/softmax overlap their latency ----
    float4 vf[12];
#pragma unroll
    for (int t = 0; t < 12; ++t) vf[t] = *(const float4*)(vc + off[t]);

    // ---- 16-lane dot reduction via DPP rotate-add (broadcasts to row) ----
#pragma unroll
    for (int t = 0; t < 12; ++t) {
        float d0 = s[t];
        d0 = dpp_radd<0x121>(d0);  // row_ror:1
        d0 = dpp_radd<0x122>(d0);  // row_ror:2
        d0 = dpp_radd<0x124>(d0);  // row_ror:4
        d0 = dpp_radd<0x128>(d0);  // row_ror:8
        s[t] = ok[t] ? d0 : -1e30f;
    }

    // ---- softmax in registers (cross-group via permlane swaps) ----
    float mx = fmaxf(fmaxf(fmaxf(fmaxf(s[0], s[1]), fmaxf(s[2], s[3])),
                           fmaxf(fmaxf(s[4], s[5]), fmaxf(s[6], s[7]))),
                     fmaxf(fmaxf(s[8], s[9]), fmaxf(s[10], s[11])));
    mx = red16_max(mx);
    mx = red32_max(mx);

    float pr[12];
#pragma unroll
    for (int t = 0; t < 12; ++t) pr[t] = __expf(s[t] - mx);  // -1e30 -> 0
    float d = ((pr[0] + pr[1]) + (pr[2] + pr[3])) +
              ((pr[4] + pr[5]) + (pr[6] + pr[7])) +
              ((pr[8] + pr[9]) + (pr[10] + pr[11]));
    d = red16_add(d);
    d = red32_add(d);
    const float inv = __builtin_amdgcn_rcpf(d);  // diag always valid -> d >= 1

    // ---- PV accumulate + cross-group reduce (permlane, no DS) ----
    float4 acc = make_float4(0.f, 0.f, 0.f, 0.f);
#pragma unroll
    for (int t = 0; t < 12; ++t) {
        acc.x += pr[t] * vf[t].x;
        acc.y += pr[t] * vf[t].y;
        acc.z += pr[t] * vf[t].z;
        acc.w += pr[t] * vf[t].w;
    }
    acc.x = red16_add(acc.x);
    acc.y = red16_add(acc.y);
    acc.z = red16_add(acc.z);
    acc.w = red16_add(acc.w);
    acc.x = red32_add(acc.x);
    acc.y = red32_add(acc.y);
    acc.z = red32_add(acc.z);
    acc.w = red32_add(acc.w);

    if (lane < 16) {
        float4 o = make_float4(acc.x * inv, acc.y * inv, acc.z * inv,
                               acc.w * inv);
        *(float4*)(oc + base) = o;
    }
}

extern "C" void kernel_launch(void* const* d_in, const int* in_sizes, int n_in,
                              void* d_out, int out_size, void* d_ws,
                              size_t ws_size, hipStream_t stream) {
    (void)in_sizes; (void)n_in; (void)out_size; (void)d_ws; (void)ws_size;
    const float* q = (const float*)d_in[0];
    const float* k = (const float*)d_in[1];
    const float* v = (const float*)d_in[2];
    // d_in[3] (mask) unused: LocalLogSymmetryMask is a deterministic function
    // of L and is recomputed analytically in-kernel.
    float* out = (float*)d_out;

    hipLaunchKernelGGL(MaskAttention_20572893347881_kernel, dim3(KBLOCKS),
                       dim3(KWAVES * 64), 0, stream, q, k, v, out);
}